// Round 8
// baseline (54.928 us; speedup 1.0000x reference)
//
#include <hip/hip_runtime.h>
#include <math.h>

#define NB 128
#define SEQ 400
#define DIN 256
#define HID 128
#define NE 6
#define NQ 300
#define NC 6
#define NROW 300
#define M_TOTAL (NB*NROW)          // 38400
#define ROWS_BLK 64
#define NBLK (M_TOTAL/ROWS_BLK)    // 600
#define KCHUNK 64
#define NCHUNK (DIN/KCHUNK)        // 4
#define TAU 2e-4f
#define OUT_BBOX_SZ (NB*NQ*4)

using short8 = __attribute__((ext_vector_type(8))) short;
using f32x4  = __attribute__((ext_vector_type(4))) float;

__device__ inline unsigned short bf16_rne(float f) {
    unsigned int u = __float_as_uint(f);
    unsigned int r = (u + 0x7FFFu + ((u >> 16) & 1u)) >> 16;
    return (unsigned short)r;
}

// ---- prep: W1 f32 -> bf16 hi, pre-swizzled+pre-chunked (ws offset 0) ----
__global__ __launch_bounds__(256)
void moe_prep(const float* __restrict__ W1, unsigned short* __restrict__ w1bf)
{
    int g = blockIdx.x * 256 + threadIdx.x;
    int k = g >> 7;          // 0..255
    int n = g & 127;         // 0..127
    unsigned short h = bf16_rne(W1[k * 128 + n]);
    int c  = k >> 6;
    int k2 = (k & 63) << 1;  // kbyte within chunk row
    w1bf[(c * 16384 + n * 128 + (k2 ^ ((n & 7) << 4))) >> 1] = h;
}

// ---- main: split-A bf16 MFMA GEMM1 + f32 GEMM2 + routing + IN-BLOCK f32 fix ----
// GEMM/routing arithmetic byte-identical to round-5 main (validated).
// Flagged near-tie rows recorded in an LDS bitmask (no global atomics) and
// recomputed in f32 by this same block before writing (r5/r7-validated fix math).
__global__ __launch_bounds__(256)
void moe_main(const float* __restrict__ features, const float* __restrict__ W1f,
              const float* __restrict__ b1,
              const unsigned short* __restrict__ w1bf, const float* __restrict__ W2,
              const float* __restrict__ b2, const float* __restrict__ ebox,
              const float* __restrict__ ecls, float* __restrict__ out)
{
    __shared__ __align__(16) char s_raw[34048];
    __shared__ __align__(16) float s_w2[HID * NE];
    __shared__ unsigned int s_flagw[2];
    __shared__ __align__(16) float s_ffix[DIN];
    __shared__ float s_pfix[HID];
    __shared__ float s_hfix[HID];

    const int t    = (int)threadIdx.x;
    const int lane = t & 63;
    const int wv   = t >> 6;
    const int row0 = (int)blockIdx.x * ROWS_BLK;
    const int r15  = lane & 15;
    const int kq4  = lane >> 4;

    if (t < 2) s_flagw[t] = 0u;
    for (int i = t; i < HID * NE; i += 256) s_w2[i] = W2[i];

    int  arow[4]; int akq[4]; long fbase[4];
    #pragma unroll
    for (int i = 0; i < 4; ++i) {
        int slot = i * 256 + t;
        int r  = slot >> 4;
        int kq = slot & 15;
        arow[i] = r; akq[i] = kq;
        int rowg = row0 + r;
        int bb = rowg / NROW;
        int ss = rowg - bb * NROW;
        fbase[i] = (long)(bb * SEQ + ss) * DIN;
    }

    f32x4 acc[4][2] = {};

    for (int c = 0; c < NCHUNK; ++c) {
        __syncthreads();
        short8 breg[4];
        const short8* bsrc = (const short8*)(w1bf) + (size_t)c * 1024;
        #pragma unroll
        for (int i = 0; i < 4; ++i) breg[i] = bsrc[i * 256 + t];
        #pragma unroll
        for (int i = 0; i < 4; ++i) {
            float4 v = *(const float4*)(features + fbase[i] + c * KCHUNK + akq[i] * 4);
            unsigned short hx = bf16_rne(v.x), hy = bf16_rne(v.y),
                           hz = bf16_rne(v.z), hw = bf16_rne(v.w);
            float lxf = v.x - __uint_as_float((unsigned int)hx << 16);
            float lyf = v.y - __uint_as_float((unsigned int)hy << 16);
            float lzf = v.z - __uint_as_float((unsigned int)hz << 16);
            float lwf = v.w - __uint_as_float((unsigned int)hw << 16);
            short4 hi4 = make_short4((short)hx, (short)hy, (short)hz, (short)hw);
            short4 lo4 = make_short4((short)bf16_rne(lxf), (short)bf16_rne(lyf),
                                     (short)bf16_rne(lzf), (short)bf16_rne(lwf));
            int off = arow[i] * 128 + ((akq[i] * 8) ^ ((arow[i] & 7) << 4));
            *(short4*)(s_raw + off)        = hi4;
            *(short4*)(s_raw + 8192 + off) = lo4;
        }
        #pragma unroll
        for (int i = 0; i < 4; ++i)
            *((short8*)(s_raw + 16384) + i * 256 + t) = breg[i];
        __syncthreads();

        #pragma unroll
        for (int ks = 0; ks < 2; ++ks) {
            const int kb = ks * 64 + kq4 * 16;
            short8 bf[2];
            #pragma unroll
            for (int nf = 0; nf < 2; ++nf) {
                int n = wv * 32 + nf * 16 + r15;
                bf[nf] = *(const short8*)(s_raw + 16384 + n * 128 + (kb ^ ((n & 7) << 4)));
            }
            #pragma unroll
            for (int mf = 0; mf < 4; ++mf) {
                int row  = mf * 16 + r15;
                int aoff = row * 128 + (kb ^ ((row & 7) << 4));
                short8 ah = *(const short8*)(s_raw + aoff);
                short8 al = *(const short8*)(s_raw + 8192 + aoff);
                #pragma unroll
                for (int nf = 0; nf < 2; ++nf) {
                    acc[mf][nf] = __builtin_amdgcn_mfma_f32_16x16x32_bf16(ah, bf[nf], acc[mf][nf], 0, 0, 0);
                    acc[mf][nf] = __builtin_amdgcn_mfma_f32_16x16x32_bf16(al, bf[nf], acc[mf][nf], 0, 0, 0);
                }
            }
        }
    }

    __syncthreads();
    float* s_h = (float*)s_raw;
    #pragma unroll
    for (int nf = 0; nf < 2; ++nf) {
        int col = wv * 32 + nf * 16 + r15;
        float bias = b1[col];
        #pragma unroll
        for (int mf = 0; mf < 4; ++mf) {
            int row = mf * 16 + kq4 * 4;
            #pragma unroll
            for (int r = 0; r < 4; ++r)
                s_h[(row + r) * 132 + col] = fmaxf(acc[mf][nf][r] + bias, 0.f);
        }
    }
    __syncthreads();

    const int lrow = t >> 2;
    const int part = t & 3;
    float l[6] = {0.f, 0.f, 0.f, 0.f, 0.f, 0.f};
    {
        const float* hp = s_h + lrow * 132 + part * 32;
        const float* wp = s_w2 + part * 32 * NE;
        #pragma unroll
        for (int g = 0; g < 8; ++g) {
            float4 h4 = *(const float4*)(hp + g * 4);
            float w[24];
            #pragma unroll
            for (int q = 0; q < 6; ++q)
                *(float4*)(w + q * 4) = *(const float4*)(wp + g * 24 + q * 4);
            #pragma unroll
            for (int e = 0; e < 6; ++e)
                l[e] += h4.x * w[e] + h4.y * w[6 + e] + h4.z * w[12 + e] + h4.w * w[18 + e];
        }
    }
    #pragma unroll
    for (int e = 0; e < 6; ++e) { l[e] += __shfl_xor(l[e], 1); l[e] += __shfl_xor(l[e], 2); }

    if (part == 0) {
        float lg[NE];
        #pragma unroll
        for (int e = 0; e < NE; ++e) lg[e] = l[e] + b2[e];
        float m = lg[0];
        #pragma unroll
        for (int e = 1; e < NE; ++e) m = fmaxf(m, lg[e]);
        float p[NE]; float psum = 0.f;
        #pragma unroll
        for (int e = 0; e < NE; ++e) { p[e] = expf(lg[e] - m); psum += p[e]; }
        #pragma unroll
        for (int e = 0; e < NE; ++e) p[e] = p[e] / psum;

        int i0 = 0; float v0 = p[0];
        #pragma unroll
        for (int e = 1; e < NE; ++e) if (p[e] > v0) { v0 = p[e]; i0 = e; }
        int i1 = -1; float v1 = -1e38f;
        #pragma unroll
        for (int e = 0; e < NE; ++e) if (e != i0 && p[e] > v1) { v1 = p[e]; i1 = e; }
        float v2 = -1e38f;
        #pragma unroll
        for (int e = 0; e < NE; ++e) if (e != i0 && e != i1 && p[e] > v2) v2 = p[e];

        int rowg = row0 + lrow;
        bool flg = (v1 - v2 < TAU);
        if (flg) atomicOr(&s_flagw[lrow >> 5], 1u << (lrow & 31));  // LDS atomic

        if (!flg) {
            float e1 = expf(v1 - v0);
            float rw0 = 1.f / (1.f + e1);
            float rw1 = e1 / (1.f + e1);

            int bb = rowg / NROW;
            int ss = rowg - bb * NROW;
            size_t bo0 = ((size_t)(i0 * NB + bb) * NQ + ss) * 4;
            size_t bo1 = ((size_t)(i1 * NB + bb) * NQ + ss) * 4;
            float4 g0 = *(const float4*)(ebox + bo0);
            float4 g1 = *(const float4*)(ebox + bo1);
            float4 ob;
            ob.x = rw0 * g0.x + rw1 * g1.x;
            ob.y = rw0 * g0.y + rw1 * g1.y;
            ob.z = rw0 * g0.z + rw1 * g1.z;
            ob.w = rw0 * g0.w + rw1 * g1.w;
            *(float4*)(out + (size_t)rowg * 4) = ob;

            size_t co0 = ((size_t)(i0 * NB + bb) * NQ + ss) * NC;
            size_t co1 = ((size_t)(i1 * NB + bb) * NQ + ss) * NC;
            float* oc = out + OUT_BBOX_SZ + (size_t)rowg * NC;
            #pragma unroll
            for (int k = 0; k < NC; ++k)
                oc[k] = rw0 * ecls[co0 + k] + rw1 * ecls[co1 + k];
        }
    }

    // ---- in-block f32 fix for this block's flagged rows (~1-2 expected) ----
    __syncthreads();
    unsigned long long fb =
        ((unsigned long long)s_flagw[1] << 32) | (unsigned long long)s_flagw[0];

    while (fb) {
        int r = (int)__builtin_ctzll(fb);
        fb &= fb - 1;
        int row = row0 + r;
        int bb = row / NROW;
        int ss = row - bb * NROW;

        s_ffix[t] = features[(size_t)(bb * SEQ + ss) * DIN + t];
        __syncthreads();

        // f32 GEMM1 for one row: thread (p = t>>7 d-half, c = t&127 col)
        const int c = t & 127;
        const int p = t >> 7;
        float a = 0.f;
        {
            const float* wp  = W1f + (size_t)p * 128 * HID + c;
            const float* fpp = s_ffix + p * 128;
            #pragma unroll 8
            for (int d = 0; d < 128; d += 4) {
                float4 f4 = *(const float4*)(fpp + d);
                a = fmaf(f4.x, wp[(size_t)(d + 0) * HID], a);
                a = fmaf(f4.y, wp[(size_t)(d + 1) * HID], a);
                a = fmaf(f4.z, wp[(size_t)(d + 2) * HID], a);
                a = fmaf(f4.w, wp[(size_t)(d + 3) * HID], a);
            }
        }
        if (p == 1) s_pfix[c] = a;
        __syncthreads();
        if (p == 0) s_hfix[c] = fmaxf(a + s_pfix[c] + b1[c], 0.f);
        __syncthreads();

        // logits + routing + write: wave 0, lane owns cols {2l, 2l+1} (r7 pattern)
        if (t < 64) {
            const int c0 = lane * 2;
            float h0 = s_hfix[c0];
            float h1 = s_hfix[c0 + 1];
            float lg[NE];
            #pragma unroll
            for (int e = 0; e < NE; ++e) {
                float v = h0 * W2[c0 * NE + e] + h1 * W2[(c0 + 1) * NE + e];
                #pragma unroll
                for (int off = 1; off < 64; off <<= 1) v += __shfl_xor(v, off);
                lg[e] = v + b2[e];
            }
            float mx = lg[0];
            #pragma unroll
            for (int e = 1; e < NE; ++e) mx = fmaxf(mx, lg[e]);
            float pr[NE]; float psum = 0.f;
            #pragma unroll
            for (int e = 0; e < NE; ++e) { pr[e] = expf(lg[e] - mx); psum += pr[e]; }
            #pragma unroll
            for (int e = 0; e < NE; ++e) pr[e] = pr[e] / psum;

            int i0 = 0; float v0 = pr[0];
            #pragma unroll
            for (int e = 1; e < NE; ++e) if (pr[e] > v0) { v0 = pr[e]; i0 = e; }
            int i1 = -1; float v1 = -1e38f;
            #pragma unroll
            for (int e = 0; e < NE; ++e) if (e != i0 && pr[e] > v1) { v1 = pr[e]; i1 = e; }

            if (lane == 0) {
                float e1 = expf(v1 - v0);
                float rw0 = 1.f / (1.f + e1);
                float rw1 = e1 / (1.f + e1);
                size_t bo0 = ((size_t)(i0 * NB + bb) * NQ + ss) * 4;
                size_t bo1 = ((size_t)(i1 * NB + bb) * NQ + ss) * 4;
                float4 g0 = *(const float4*)(ebox + bo0);
                float4 g1 = *(const float4*)(ebox + bo1);
                float4 ob;
                ob.x = rw0 * g0.x + rw1 * g1.x;
                ob.y = rw0 * g0.y + rw1 * g1.y;
                ob.z = rw0 * g0.z + rw1 * g1.z;
                ob.w = rw0 * g0.w + rw1 * g1.w;
                *(float4*)(out + (size_t)row * 4) = ob;
                size_t co0 = ((size_t)(i0 * NB + bb) * NQ + ss) * NC;
                size_t co1 = ((size_t)(i1 * NB + bb) * NQ + ss) * NC;
                float* oc = out + OUT_BBOX_SZ + (size_t)row * NC;
                #pragma unroll
                for (int k = 0; k < NC; ++k)
                    oc[k] = rw0 * ecls[co0 + k] + rw1 * ecls[co1 + k];
            }
        }
        __syncthreads();
    }
}

extern "C" void kernel_launch(void* const* d_in, const int* in_sizes, int n_in,
                              void* d_out, int out_size, void* d_ws, size_t ws_size,
                              hipStream_t stream)
{
    const float* features = (const float*)d_in[0];
    const float* W1   = (const float*)d_in[1];
    const float* b1   = (const float*)d_in[2];
    const float* W2   = (const float*)d_in[3];
    const float* b2   = (const float*)d_in[4];
    const float* ebox = (const float*)d_in[5];
    const float* ecls = (const float*)d_in[6];
    float* out = (float*)d_out;

    unsigned short* w1bf = (unsigned short*)d_ws;

    hipLaunchKernelGGL(moe_prep, dim3(128), dim3(256), 0, stream, W1, w1bf);
    hipLaunchKernelGGL(moe_main, dim3(NBLK), dim3(256), 0, stream,
                       features, W1, b1, w1bf, W2, b2, ebox, ecls, out);
}

// Round 9
// 43.934 us; speedup vs baseline: 1.2502x; 1.2502x over previous
//
#include <hip/hip_runtime.h>
#include <math.h>

#define NB 128
#define SEQ 400
#define DIN 256
#define HID 128
#define NE 6
#define NQ 300
#define NC 6
#define NROW 300
#define M_TOTAL (NB*NROW)          // 38400
#define ROWS_BLK 64
#define NBLK (M_TOTAL/ROWS_BLK)    // 600
#define KCHUNK 64
#define NCHUNK (DIN/KCHUNK)        // 4
#define TAU 2e-4f
#define OUT_BBOX_SZ (NB*NQ*4)
#define BM_WORDS (NBLK*2)          // 1200
#define FIX_BLOCKS 128
#define FIX_GWAVES (FIX_BLOCKS*16) // 2048

// workspace layout (bytes):
//   [0, 65536)       : pre-swizzled bf16 W1 (hi plane), 4 chunks x 16KB
//   [65536, +4800)   : flag bitmap, 2 words per main-block (plain stores)
#define WS_BM_OFF 65536

using short8 = __attribute__((ext_vector_type(8))) short;
using f32x4  = __attribute__((ext_vector_type(4))) float;

__device__ inline unsigned short bf16_rne(float f) {
    unsigned int u = __float_as_uint(f);
    unsigned int r = (u + 0x7FFFu + ((u >> 16) & 1u)) >> 16;
    return (unsigned short)r;
}

// ---- prep: W1 f32 -> bf16 hi, pre-swizzled+pre-chunked (r5-verbatim) ----
__global__ __launch_bounds__(256)
void moe_prep(const float* __restrict__ W1, unsigned short* __restrict__ w1bf)
{
    int g = blockIdx.x * 256 + threadIdx.x;
    int k = g >> 7;          // 0..255
    int n = g & 127;         // 0..127
    unsigned short h = bf16_rne(W1[k * 128 + n]);
    int c  = k >> 6;
    int k2 = (k & 63) << 1;  // kbyte within chunk row
    w1bf[(c * 16384 + n * 128 + (k2 ^ ((n & 7) << 4))) >> 1] = h;
}

// ---- main: split-A bf16 MFMA GEMM1 + f32 GEMM2 + routing (r5-verbatim compute).
// Flags -> LDS bitmask (r8-validated) -> plain per-block bitmap stores. No atomics,
// no fix tail: flagged rows are skipped here and written by moe_fix.
__global__ __launch_bounds__(256)
void moe_main(const float* __restrict__ features, const float* __restrict__ b1,
              const unsigned short* __restrict__ w1bf, const float* __restrict__ W2,
              const float* __restrict__ b2, const float* __restrict__ ebox,
              const float* __restrict__ ecls, unsigned int* __restrict__ bitmap,
              float* __restrict__ out)
{
    __shared__ __align__(16) char s_raw[34048];
    __shared__ __align__(16) float s_w2[HID * NE];
    __shared__ unsigned int s_flagw[2];

    const int t    = (int)threadIdx.x;
    const int lane = t & 63;
    const int wv   = t >> 6;
    const int row0 = (int)blockIdx.x * ROWS_BLK;
    const int r15  = lane & 15;
    const int kq4  = lane >> 4;

    if (t < 2) s_flagw[t] = 0u;
    for (int i = t; i < HID * NE; i += 256) s_w2[i] = W2[i];

    int  arow[4]; int akq[4]; long fbase[4];
    #pragma unroll
    for (int i = 0; i < 4; ++i) {
        int slot = i * 256 + t;
        int r  = slot >> 4;
        int kq = slot & 15;
        arow[i] = r; akq[i] = kq;
        int rowg = row0 + r;
        int bb = rowg / NROW;
        int ss = rowg - bb * NROW;
        fbase[i] = (long)(bb * SEQ + ss) * DIN;
    }

    f32x4 acc[4][2] = {};

    for (int c = 0; c < NCHUNK; ++c) {
        __syncthreads();
        short8 breg[4];
        const short8* bsrc = (const short8*)(w1bf) + (size_t)c * 1024;
        #pragma unroll
        for (int i = 0; i < 4; ++i) breg[i] = bsrc[i * 256 + t];
        #pragma unroll
        for (int i = 0; i < 4; ++i) {
            float4 v = *(const float4*)(features + fbase[i] + c * KCHUNK + akq[i] * 4);
            unsigned short hx = bf16_rne(v.x), hy = bf16_rne(v.y),
                           hz = bf16_rne(v.z), hw = bf16_rne(v.w);
            float lxf = v.x - __uint_as_float((unsigned int)hx << 16);
            float lyf = v.y - __uint_as_float((unsigned int)hy << 16);
            float lzf = v.z - __uint_as_float((unsigned int)hz << 16);
            float lwf = v.w - __uint_as_float((unsigned int)hw << 16);
            short4 hi4 = make_short4((short)hx, (short)hy, (short)hz, (short)hw);
            short4 lo4 = make_short4((short)bf16_rne(lxf), (short)bf16_rne(lyf),
                                     (short)bf16_rne(lzf), (short)bf16_rne(lwf));
            int off = arow[i] * 128 + ((akq[i] * 8) ^ ((arow[i] & 7) << 4));
            *(short4*)(s_raw + off)        = hi4;
            *(short4*)(s_raw + 8192 + off) = lo4;
        }
        #pragma unroll
        for (int i = 0; i < 4; ++i)
            *((short8*)(s_raw + 16384) + i * 256 + t) = breg[i];
        __syncthreads();

        #pragma unroll
        for (int ks = 0; ks < 2; ++ks) {
            const int kb = ks * 64 + kq4 * 16;
            short8 bf[2];
            #pragma unroll
            for (int nf = 0; nf < 2; ++nf) {
                int n = wv * 32 + nf * 16 + r15;
                bf[nf] = *(const short8*)(s_raw + 16384 + n * 128 + (kb ^ ((n & 7) << 4)));
            }
            #pragma unroll
            for (int mf = 0; mf < 4; ++mf) {
                int row  = mf * 16 + r15;
                int aoff = row * 128 + (kb ^ ((row & 7) << 4));
                short8 ah = *(const short8*)(s_raw + aoff);
                short8 al = *(const short8*)(s_raw + 8192 + aoff);
                #pragma unroll
                for (int nf = 0; nf < 2; ++nf) {
                    acc[mf][nf] = __builtin_amdgcn_mfma_f32_16x16x32_bf16(ah, bf[nf], acc[mf][nf], 0, 0, 0);
                    acc[mf][nf] = __builtin_amdgcn_mfma_f32_16x16x32_bf16(al, bf[nf], acc[mf][nf], 0, 0, 0);
                }
            }
        }
    }

    __syncthreads();
    float* s_h = (float*)s_raw;
    #pragma unroll
    for (int nf = 0; nf < 2; ++nf) {
        int col = wv * 32 + nf * 16 + r15;
        float bias = b1[col];
        #pragma unroll
        for (int mf = 0; mf < 4; ++mf) {
            int row = mf * 16 + kq4 * 4;
            #pragma unroll
            for (int r = 0; r < 4; ++r)
                s_h[(row + r) * 132 + col] = fmaxf(acc[mf][nf][r] + bias, 0.f);
        }
    }
    __syncthreads();

    const int lrow = t >> 2;
    const int part = t & 3;
    float l[6] = {0.f, 0.f, 0.f, 0.f, 0.f, 0.f};
    {
        const float* hp = s_h + lrow * 132 + part * 32;
        const float* wp = s_w2 + part * 32 * NE;
        #pragma unroll
        for (int g = 0; g < 8; ++g) {
            float4 h4 = *(const float4*)(hp + g * 4);
            float w[24];
            #pragma unroll
            for (int q = 0; q < 6; ++q)
                *(float4*)(w + q * 4) = *(const float4*)(wp + g * 24 + q * 4);
            #pragma unroll
            for (int e = 0; e < 6; ++e)
                l[e] += h4.x * w[e] + h4.y * w[6 + e] + h4.z * w[12 + e] + h4.w * w[18 + e];
        }
    }
    #pragma unroll
    for (int e = 0; e < 6; ++e) { l[e] += __shfl_xor(l[e], 1); l[e] += __shfl_xor(l[e], 2); }

    if (part == 0) {
        float lg[NE];
        #pragma unroll
        for (int e = 0; e < NE; ++e) lg[e] = l[e] + b2[e];
        float m = lg[0];
        #pragma unroll
        for (int e = 1; e < NE; ++e) m = fmaxf(m, lg[e]);
        float p[NE]; float psum = 0.f;
        #pragma unroll
        for (int e = 0; e < NE; ++e) { p[e] = expf(lg[e] - m); psum += p[e]; }
        #pragma unroll
        for (int e = 0; e < NE; ++e) p[e] = p[e] / psum;

        int i0 = 0; float v0 = p[0];
        #pragma unroll
        for (int e = 1; e < NE; ++e) if (p[e] > v0) { v0 = p[e]; i0 = e; }
        int i1 = -1; float v1 = -1e38f;
        #pragma unroll
        for (int e = 0; e < NE; ++e) if (e != i0 && p[e] > v1) { v1 = p[e]; i1 = e; }
        float v2 = -1e38f;
        #pragma unroll
        for (int e = 0; e < NE; ++e) if (e != i0 && e != i1 && p[e] > v2) v2 = p[e];

        int rowg = row0 + lrow;
        bool flg = (v1 - v2 < TAU);
        if (flg) atomicOr(&s_flagw[lrow >> 5], 1u << (lrow & 31));  // LDS atomic

        if (!flg) {
            float e1 = expf(v1 - v0);
            float rw0 = 1.f / (1.f + e1);
            float rw1 = e1 / (1.f + e1);

            int bb = rowg / NROW;
            int ss = rowg - bb * NROW;
            size_t bo0 = ((size_t)(i0 * NB + bb) * NQ + ss) * 4;
            size_t bo1 = ((size_t)(i1 * NB + bb) * NQ + ss) * 4;
            float4 g0 = *(const float4*)(ebox + bo0);
            float4 g1 = *(const float4*)(ebox + bo1);
            float4 ob;
            ob.x = rw0 * g0.x + rw1 * g1.x;
            ob.y = rw0 * g0.y + rw1 * g1.y;
            ob.z = rw0 * g0.z + rw1 * g1.z;
            ob.w = rw0 * g0.w + rw1 * g1.w;
            *(float4*)(out + (size_t)rowg * 4) = ob;

            size_t co0 = ((size_t)(i0 * NB + bb) * NQ + ss) * NC;
            size_t co1 = ((size_t)(i1 * NB + bb) * NQ + ss) * NC;
            float* oc = out + OUT_BBOX_SZ + (size_t)rowg * NC;
            #pragma unroll
            for (int k = 0; k < NC; ++k)
                oc[k] = rw0 * ecls[co0 + k] + rw1 * ecls[co1 + k];
        }
    }

    __syncthreads();
    if (t == 0) {
        bitmap[(size_t)blockIdx.x * 2 + 0] = s_flagw[0];
        bitmap[(size_t)blockIdx.x * 2 + 1] = s_flagw[1];
    }
}

// ---- fix: balanced wave-per-flagged-row f32 recompute.
// Bitmap -> LDS prefix-sum -> wave g owns ordinals g, g+2048, ... (<=1 row/wave).
// W1 staged in LDS (r7-validated); per-row math verbatim from r7's fix.
__global__ __launch_bounds__(1024)
void moe_fix(const float* __restrict__ features, const float* __restrict__ W1,
             const float* __restrict__ b1, const float* __restrict__ W2,
             const float* __restrict__ b2, const float* __restrict__ ebox,
             const float* __restrict__ ecls, const unsigned int* __restrict__ bitmap,
             float* __restrict__ out)
{
    __shared__ float s_w1[DIN * HID];   // 128 KB
    __shared__ unsigned int s_bm[BM_WORDS];
    __shared__ int s_a[BM_WORDS];
    __shared__ int s_b[BM_WORDS];

    const int t    = (int)threadIdx.x;
    const int lane = t & 63;
    const int gw   = ((int)blockIdx.x << 4) + (t >> 6);   // global wave id

    // stage W1 (f32, 128 KB) into LDS: 1024 threads x 8 float4 (r7-verbatim)
    {
        const float4* src = (const float4*)W1;
        float4* dst = (float4*)s_w1;
        #pragma unroll
        for (int i = 0; i < 8; ++i) dst[i * 1024 + t] = src[i * 1024 + t];
    }
    // stage bitmap + per-word popcounts
    for (int i = t; i < BM_WORDS; i += 1024) {
        unsigned int w = bitmap[i];
        s_bm[i] = w;
        s_a[i] = (int)__popc(w);
    }
    __syncthreads();

    // Hillis-Steele inclusive scan over BM_WORDS, ping-pong s_a/s_b
    int* src = s_a; int* dst = s_b;
    for (int s = 1; s < BM_WORDS; s <<= 1) {
        for (int i = t; i < BM_WORDS; i += 1024)
            dst[i] = src[i] + (i >= s ? src[i - s] : 0);
        __syncthreads();
        int* tmp = src; src = dst; dst = tmp;
    }
    const int N = src[BM_WORDS - 1];

    const int c0 = lane * 2;   // this lane's two hidden cols (r7 pattern)

    for (int o = gw; o < N; o += FIX_GWAVES) {
        // find word containing ordinal o: smallest i with incl_pfx[i] > o
        int lo = 0, hi = BM_WORDS - 1;
        while (lo < hi) {
            int mid = (lo + hi) >> 1;
            if (src[mid] > o) hi = mid; else lo = mid + 1;
        }
        int excl = lo ? src[lo - 1] : 0;
        int k = o - excl;                  // k-th set bit within word lo
        unsigned int w = s_bm[lo];
        for (int j = 0; j < k; ++j) w &= w - 1;
        int row = lo * 32 + (int)__builtin_ctz(w);

        int bb = row / NROW;
        int ss = row - bb * NROW;
        const float* fp = features + (size_t)(bb * SEQ + ss) * DIN;

        float a0 = 0.f, a1 = 0.f;
        #pragma unroll 8
        for (int d = 0; d < DIN; d += 4) {
            float4 f4 = *(const float4*)(fp + d);
            float2 w0 = *(const float2*)(s_w1 + (d + 0) * HID + c0);
            float2 w1 = *(const float2*)(s_w1 + (d + 1) * HID + c0);
            float2 w2 = *(const float2*)(s_w1 + (d + 2) * HID + c0);
            float2 w3 = *(const float2*)(s_w1 + (d + 3) * HID + c0);
            a0 = fmaf(f4.x, w0.x, a0); a1 = fmaf(f4.x, w0.y, a1);
            a0 = fmaf(f4.y, w1.x, a0); a1 = fmaf(f4.y, w1.y, a1);
            a0 = fmaf(f4.z, w2.x, a0); a1 = fmaf(f4.z, w2.y, a1);
            a0 = fmaf(f4.w, w3.x, a0); a1 = fmaf(f4.w, w3.y, a1);
        }
        float h0 = fmaxf(a0 + b1[c0], 0.f);
        float h1 = fmaxf(a1 + b1[c0 + 1], 0.f);

        float lg[NE];
        #pragma unroll
        for (int e = 0; e < NE; ++e) {
            float v = h0 * W2[c0 * NE + e] + h1 * W2[(c0 + 1) * NE + e];
            #pragma unroll
            for (int off = 1; off < 64; off <<= 1) v += __shfl_xor(v, off);
            lg[e] = v + b2[e];
        }
        float mx = lg[0];
        #pragma unroll
        for (int e = 1; e < NE; ++e) mx = fmaxf(mx, lg[e]);
        float pr[NE]; float psum = 0.f;
        #pragma unroll
        for (int e = 0; e < NE; ++e) { pr[e] = expf(lg[e] - mx); psum += pr[e]; }
        #pragma unroll
        for (int e = 0; e < NE; ++e) pr[e] = pr[e] / psum;

        int i0 = 0; float v0 = pr[0];
        #pragma unroll
        for (int e = 1; e < NE; ++e) if (pr[e] > v0) { v0 = pr[e]; i0 = e; }
        int i1 = -1; float v1 = -1e38f;
        #pragma unroll
        for (int e = 0; e < NE; ++e) if (e != i0 && pr[e] > v1) { v1 = pr[e]; i1 = e; }

        if (lane == 0) {
            float e1 = expf(v1 - v0);
            float rw0 = 1.f / (1.f + e1);
            float rw1 = e1 / (1.f + e1);
            size_t bo0 = ((size_t)(i0 * NB + bb) * NQ + ss) * 4;
            size_t bo1 = ((size_t)(i1 * NB + bb) * NQ + ss) * 4;
            float4 g0 = *(const float4*)(ebox + bo0);
            float4 g1 = *(const float4*)(ebox + bo1);
            float4 ob;
            ob.x = rw0 * g0.x + rw1 * g1.x;
            ob.y = rw0 * g0.y + rw1 * g1.y;
            ob.z = rw0 * g0.z + rw1 * g1.z;
            ob.w = rw0 * g0.w + rw1 * g1.w;
            *(float4*)(out + (size_t)row * 4) = ob;
            size_t co0 = ((size_t)(i0 * NB + bb) * NQ + ss) * NC;
            size_t co1 = ((size_t)(i1 * NB + bb) * NQ + ss) * NC;
            float* oc = out + OUT_BBOX_SZ + (size_t)row * NC;
            #pragma unroll
            for (int kk = 0; kk < NC; ++kk)
                oc[kk] = rw0 * ecls[co0 + kk] + rw1 * ecls[co1 + kk];
        }
    }
}

extern "C" void kernel_launch(void* const* d_in, const int* in_sizes, int n_in,
                              void* d_out, int out_size, void* d_ws, size_t ws_size,
                              hipStream_t stream)
{
    const float* features = (const float*)d_in[0];
    const float* W1   = (const float*)d_in[1];
    const float* b1   = (const float*)d_in[2];
    const float* W2   = (const float*)d_in[3];
    const float* b2   = (const float*)d_in[4];
    const float* ebox = (const float*)d_in[5];
    const float* ecls = (const float*)d_in[6];
    float* out = (float*)d_out;

    unsigned short* w1bf   = (unsigned short*)d_ws;
    unsigned int*   bitmap = (unsigned int*)((char*)d_ws + WS_BM_OFF);

    hipLaunchKernelGGL(moe_prep, dim3(128), dim3(256), 0, stream, W1, w1bf);
    hipLaunchKernelGGL(moe_main, dim3(NBLK), dim3(256), 0, stream,
                       features, b1, w1bf, W2, b2, ebox, ecls, bitmap, out);
    hipLaunchKernelGGL(moe_fix, dim3(FIX_BLOCKS), dim3(1024), 0, stream,
                       features, W1, b1, W2, b2, ebox, ecls, bitmap, out);
}